// Round 9
// baseline (281.323 us; speedup 1.0000x reference)
//
#include <hip/hip_runtime.h>
#include <hip/hip_bf16.h>
#include <stdint.h>

// Transformer layer: S=2048, B=2, D=1024, H=16, DH=64, FF=4096. fp32 in/out.
// Strategy: fp32 LN/softmax/accum, bf16 MFMA (16x16x32) for all GEMMs.

#define S_LEN 2048
#define BATCH 2
#define DMODEL 1024
#define NHEAD 16
#define DHEAD 64
#define FFDIM 4096
#define MROWS (S_LEN * BATCH)  // 4096 rows, row index = s*B + b

typedef unsigned short u16;
typedef __attribute__((ext_vector_type(8))) __bf16 bf16x8;
typedef __attribute__((ext_vector_type(4))) float f32x4;
typedef __attribute__((ext_vector_type(4))) u16 u16x4;

__device__ inline u16 f2bf(float f) {
  union { float f; unsigned u; } v; v.f = f;
  unsigned r = v.u + 0x7fffu + ((v.u >> 16) & 1u);  // round-to-nearest-even
  return (u16)(r >> 16);
}

__device__ inline f32x4 mfma16(bf16x8 a, bf16x8 b, f32x4 c) {
  return __builtin_amdgcn_mfma_f32_16x16x32_bf16(a, b, c, 0, 0, 0);
}

// async global->LDS, 16B per lane. LDS dest must be wave-uniform base; HW adds lane*16.
__device__ inline void gload_lds16(const u16* g, u16* l) {
  __builtin_amdgcn_global_load_lds(
      (const __attribute__((address_space(1))) unsigned int*)g,
      (__attribute__((address_space(3))) unsigned int*)l, 16, 0, 0);
}

__device__ inline uint32_t cvt_pk_bf16(float lo, float hi) {
  uint32_t r;
  asm("v_cvt_pk_bf16_f32 %0, %1, %2" : "=v"(r) : "v"(lo), "v"(hi));
  return r;
}

// ---------------- LayerNorm: fp32 in -> bf16 out ----------------
__global__ __launch_bounds__(256) void ln_kernel(const float* __restrict__ x,
                                                 const float* __restrict__ gam,
                                                 const float* __restrict__ bet,
                                                 u16* __restrict__ out) {
  int row = blockIdx.x;
  int tid = threadIdx.x;
  const float4* xr = (const float4*)(x + (size_t)row * DMODEL);
  float4 v = xr[tid];
  float s = v.x + v.y + v.z + v.w;
  float ss = v.x * v.x + v.y * v.y + v.z * v.z + v.w * v.w;
#pragma unroll
  for (int m = 1; m < 64; m <<= 1) {
    s += __shfl_xor(s, m);
    ss += __shfl_xor(ss, m);
  }
  __shared__ float red[8];
  int w = tid >> 6, lane = tid & 63;
  if (lane == 0) { red[w] = s; red[4 + w] = ss; }
  __syncthreads();
  s = red[0] + red[1] + red[2] + red[3];
  ss = red[4] + red[5] + red[6] + red[7];
  float mu = s * (1.f / DMODEL);
  float var = ss * (1.f / DMODEL) - mu * mu;
  float rstd = rsqrtf(var + 1e-5f);
  float4 gv = ((const float4*)gam)[tid];
  float4 bv = ((const float4*)bet)[tid];
  u16x4 o;
  o.x = f2bf((v.x - mu) * rstd * gv.x + bv.x);
  o.y = f2bf((v.y - mu) * rstd * gv.y + bv.y);
  o.z = f2bf((v.z - mu) * rstd * gv.z + bv.z);
  o.w = f2bf((v.w - mu) * rstd * gv.w + bv.w);
  *(u16x4*)(out + (size_t)row * DMODEL + tid * 4) = o;
}

// ---------------- fused weight transpose-cast: all 6 weights in ONE launch ----------------
__global__ __launch_bounds__(256) void transpose_all(const float* __restrict__ wq,
                                                     const float* __restrict__ wk,
                                                     const float* __restrict__ wv,
                                                     const float* __restrict__ wo,
                                                     const float* __restrict__ w1,
                                                     const float* __restrict__ w2,
                                                     u16* __restrict__ wqkvt, u16* __restrict__ wot,
                                                     u16* __restrict__ w1t, u16* __restrict__ w2t) {
  int idx = blockIdx.x;
  const float* in;
  u16* out;
  int R, C;
  if (idx < 3072) {
    int which = idx >> 10;
    in = (which == 0) ? wq : (which == 1) ? wk : wv;
    out = wqkvt + (size_t)which * 1024 * 1024;
    R = 1024; C = 1024;
    idx &= 1023;
  } else if (idx < 4096) {
    in = wo; out = wot; R = 1024; C = 1024; idx -= 3072;
  } else if (idx < 8192) {
    in = w1; out = w1t; R = 1024; C = 4096; idx -= 4096;
  } else {
    in = w2; out = w2t; R = 4096; C = 1024; idx -= 8192;
  }
  int ntx = C >> 5;
  int tc = idx % ntx, tr = idx / ntx;
  int c0 = tc * 32, r0 = tr * 32;
  __shared__ u16 tile[32][33];
  int tx = threadIdx.x & 31, grp = threadIdx.x >> 5;
#pragma unroll
  for (int i = 0; i < 4; i++) {
    int r = grp * 4 + i;
    tile[r][tx] = f2bf(in[(size_t)(r0 + r) * C + c0 + tx]);
  }
  __syncthreads();
#pragma unroll
  for (int i = 0; i < 4; i++) {
    int rr = grp * 4 + i;
    out[(size_t)(c0 + rr) * R + r0 + tx] = tile[tx][rr];
  }
}

// ---------------- V slice of qkv -> Vt[bh][dh][s] ----------------
__global__ __launch_bounds__(256) void transpose_v(const u16* __restrict__ qkv,
                                                   u16* __restrict__ vt) {
  __shared__ u16 tile[32][33];
  int bh = blockIdx.z;
  int b = bh >> 4;
  int s0 = blockIdx.x * 32, d0 = blockIdx.y * 32;
  int h = bh & 15;
  int tx = threadIdx.x & 31, grp = threadIdx.x >> 5;
#pragma unroll
  for (int i = 0; i < 4; i++) {
    int sl = grp * 4 + i;
    tile[sl][tx] = qkv[(size_t)((s0 + sl) * BATCH + b) * 3072 + 2048 + h * DHEAD + d0 + tx];
  }
  __syncthreads();
#pragma unroll
  for (int i = 0; i < 4; i++) {
    int dl = grp * 4 + i;
    vt[((size_t)bh * DHEAD + d0 + dl) * S_LEN + s0 + tx] = tile[tx][dl];
  }
}

// ---------------- GEMM 8-phase 256x256 (counted-vmcnt, no drain) ----------------
// C[M][N] = A[M][K] @ Bt[N][K]^T, 512 thr = 8 waves (2M x 4N), BK=64, 128KB LDS dbuf.
// Tile t = 4 quadrant phases; phase q: {stage half-tile Hq of t+1 || ds_read quadrant-q
// frags || barrier || setprio + 16 MFMA || barrier}.  Certification: at q0, AFTER
// issuing H0(t+1), vmcnt(2) certifies ALL 8 older loads (tile t complete) while the
// new half stays in flight; barrier makes it cross-wave. vmcnt never drains to 0 in
// the main loop (R6's fatal flaw removed). buf[nxt] staging begins >= 1 barrier after
// its last reader (t-1 q3 close barrier) -> race-free.
// MODE 0: bf16 out.  MODE 2: bf16 out = relu(acc + bias).
template <int MODE>
__global__ __launch_bounds__(512, 2) void gemm8(const u16* __restrict__ A,
                                                const u16* __restrict__ Bt,
                                                void* __restrict__ Cout,
                                                const float* __restrict__ bias, int M, int N,
                                                int K) {
  __shared__ __align__(16) u16 As[2][256 * 64];
  __shared__ __align__(16) u16 Bs[2][256 * 64];

  int nwgx = gridDim.x;
  int nwg = nwgx * gridDim.y;
  int f = blockIdx.y * nwgx + blockIdx.x;
  int nf = (f & 7) * (nwg >> 3) + (f >> 3);  // grids %8==0: bijective
  int bx = nf % nwgx, by = nf / nwgx;
  int bm0 = by * 256, bn0 = bx * 256;
  int tid = threadIdx.x, w = tid >> 6, lane = tid & 63;
  int g = lane >> 4, l15 = lane & 15;
  int lr = lane >> 3, ch = lane & 7;
  int srcch = (ch ^ lr) * 8;                 // pre-swizzled source chunk (rule 21c)
  int wm = (w >> 2) * 128, wn = (w & 3) * 64;

  f32x4 acc[8][4];
#pragma unroll
  for (int i = 0; i < 8; i++)
#pragma unroll
    for (int j = 0; j < 4; j++) {
      f32x4 z = {0.f, 0.f, 0.f, 0.f};
      acc[i][j] = z;
    }

  // stage one half-tile: hh 0/1 -> A rows [hh*128,+128); hh 2/3 -> B rows [(hh-2)*128,+128)
  auto stageHalf = [&](int t, int hh) {
    int k0 = t << 6;
    int buf = t & 1;
    const u16* src = (hh < 2) ? A : Bt;
    u16* dstbase = (hh < 2) ? As[buf] : Bs[buf];
    int base0 = (hh < 2) ? bm0 : bn0;
    int h = hh & 1;
#pragma unroll
    for (int rd = 0; rd < 2; rd++) {
      int rb = h * 128 + w * 16 + rd * 8;  // lane's row = rb + lr; row&7 == lr
      gload_lds16(src + (size_t)(base0 + rb + lr) * K + k0 + srcch, &dstbase[rb * 64]);
    }
  };

  int nkt = K >> 6;
  // prologue: stage tile 0 fully, drain once (outside the loop), barrier
#pragma unroll
  for (int hh = 0; hh < 4; hh++) stageHalf(0, hh);
  asm volatile("s_waitcnt vmcnt(0)" ::: "memory");
  __builtin_amdgcn_s_barrier();

  for (int t = 0; t < nkt; ++t) {
    int cur = t & 1;
    bool pf = (t + 1 < nkt);
#pragma unroll
    for (int q = 0; q < 4; q++) {
      if (pf) stageHalf(t + 1, q);
      if (q == 0) {
        if (pf)
          asm volatile("s_waitcnt vmcnt(2)" ::: "memory");  // tile t landed; H0(t+1) flies
        else
          asm volatile("s_waitcnt vmcnt(0)" ::: "memory");
        __builtin_amdgcn_s_barrier();  // cross-wave: tile t visible in LDS
      }
      // ds_read quadrant q fragments (certified by q0's barrier)
      bf16x8 af[4][2], bfr[2][2];
#pragma unroll
      for (int i = 0; i < 4; i++) {
        int row = wm + (q & 1) * 64 + i * 16 + l15;
#pragma unroll
        for (int ks = 0; ks < 2; ks++)
          af[i][ks] = *(const bf16x8*)&As[cur][row * 64 + (((ks * 4 + g) ^ (row & 7)) * 8)];
      }
#pragma unroll
      for (int j = 0; j < 2; j++) {
        int row = wn + (q >> 1) * 32 + j * 16 + l15;
#pragma unroll
        for (int ks = 0; ks < 2; ks++)
          bfr[j][ks] = *(const bf16x8*)&Bs[cur][row * 64 + (((ks * 4 + g) ^ (row & 7)) * 8)];
      }
      __builtin_amdgcn_s_barrier();  // align MFMA clusters
      __builtin_amdgcn_s_setprio(1);
#pragma unroll
      for (int ks = 0; ks < 2; ks++)
#pragma unroll
        for (int i = 0; i < 4; i++)
#pragma unroll
          for (int j = 0; j < 2; j++)
            acc[(q & 1) * 4 + i][(q >> 1) * 2 + j] =
                mfma16(af[i][ks], bfr[j][ks], acc[(q & 1) * 4 + i][(q >> 1) * 2 + j]);
      __builtin_amdgcn_s_setprio(0);
      __builtin_amdgcn_s_barrier();  // phase close (q3's instance protects buf reuse)
    }
  }

  // epilogue: D layout col = lane&15, row = 4*(lane>>4) + r
#pragma unroll
  for (int n2 = 0; n2 < 4; n2++) {
    int col = bn0 + wn + n2 * 16 + l15;
    float bval = (MODE == 2) ? bias[col] : 0.f;
#pragma unroll
    for (int m2 = 0; m2 < 8; m2++)
#pragma unroll
      for (int r = 0; r < 4; r++) {
        int row = bm0 + wm + m2 * 16 + g * 4 + r;
        float v = acc[m2][n2][r] + bval;
        if (MODE == 2) v = fmaxf(v, 0.f);
        ((u16*)Cout)[(size_t)row * N + col] = f2bf(v);
      }
  }
}

// ---------------- GEMM (R5-proven): BK=64, XOR-swizzled LDS, counted-vmcnt 2-phase ----------------
// MODE 1: fp32 out = acc + res.  MODE 3: fp32 out = acc + bias + res.
template <int MODE, int BN>
__global__ __launch_bounds__(256) void gemm_bt(const u16* __restrict__ A,
                                               const u16* __restrict__ Bt, void* __restrict__ Cout,
                                               const float* __restrict__ bias,
                                               const float* __restrict__ res, int M, int N, int K) {
  __shared__ __align__(16) u16 As[2][128 * 64];
  __shared__ __align__(16) u16 Bs[2][BN * 64];
  constexpr int NLOADS = 4 + BN / 32;

  int nwg = gridDim.x * gridDim.y;
  int f = blockIdx.y * gridDim.x + blockIdx.x;
  int nf = ((nwg & 7) == 0) ? ((f & 7) * (nwg >> 3) + (f >> 3)) : f;
  int bx = nf % gridDim.x, by = nf / gridDim.x;

  int bm0 = by * 128, bn0 = bx * BN;
  int tid = threadIdx.x, w = tid >> 6, lane = tid & 63;
  int g = lane >> 4, l15 = lane & 15;
  int lr = lane >> 3, ch = lane & 7;
  int srcch = (ch ^ lr) * 8;
  int wm = (w >> 1) * 64, wn = (w & 1) * (BN / 2);
  const int NJ = BN / 32;

  f32x4 acc[4][NJ];
#pragma unroll
  for (int i = 0; i < 4; i++)
#pragma unroll
    for (int j = 0; j < NJ; j++) {
      f32x4 z = {0.f, 0.f, 0.f, 0.f};
      acc[i][j] = z;
    }

  auto stage = [&](int k0, int buf) {
#pragma unroll
    for (int rd = 0; rd < 4; rd++) {
      int rb = (rd * 4 + w) * 8;
      gload_lds16(A + (size_t)(bm0 + rb + lr) * K + k0 + srcch, &As[buf][rb * 64]);
    }
#pragma unroll
    for (int rd = 0; rd < BN / 32; rd++) {
      int rb = (rd * 4 + w) * 8;
      gload_lds16(Bt + (size_t)(bn0 + rb + lr) * K + k0 + srcch, &Bs[buf][rb * 64]);
    }
  };

  int nkt = K >> 6;
  stage(0, 0);
  asm volatile("s_waitcnt vmcnt(0)" ::: "memory");
  __builtin_amdgcn_s_barrier();

  for (int kt = 0; kt < nkt; ++kt) {
    int cur = kt & 1;
    if (kt + 1 < nkt) {
      stage((kt + 1) << 6, cur ^ 1);
      asm volatile("s_waitcnt vmcnt(%0)" ::"n"(NLOADS) : "memory");
    } else {
      asm volatile("s_waitcnt vmcnt(0)" ::: "memory");
    }
    __builtin_amdgcn_s_barrier();
#pragma unroll
    for (int kk = 0; kk < 2; kk++) {
      bf16x8 af[4], bfr[NJ];
#pragma unroll
      for (int i = 0; i < 4; i++) {
        int row = wm + i * 16 + l15;
        af[i] = *(const bf16x8*)&As[cur][row * 64 + (((kk * 4 + g) ^ (row & 7)) * 8)];
      }
#pragma unroll
      for (int j = 0; j < NJ; j++) {
        int row = wn + j * 16 + l15;
        bfr[j] = *(const bf16x8*)&Bs[cur][row * 64 + (((kk * 4 + g) ^ (row & 7)) * 8)];
      }
#pragma unroll
      for (int i = 0; i < 4; i++)
#pragma unroll
        for (int j = 0; j < NJ; j++) acc[i][j] = mfma16(af[i], bfr[j], acc[i][j]);
    }
    __builtin_amdgcn_s_barrier();
  }

#pragma unroll
  for (int i = 0; i < 4; i++)
#pragma unroll
    for (int j = 0; j < NJ; j++) {
      int col = bn0 + wn + j * 16 + l15;
      float bval = (MODE == 3) ? bias[col] : 0.f;
#pragma unroll
      for (int r = 0; r < 4; r++) {
        int row = bm0 + wm + i * 16 + g * 4 + r;
        size_t idx = (size_t)row * N + col;
        ((float*)Cout)[idx] = acc[i][j][r] + bval + res[idx];
      }
    }
}

// ---------------- flash attention v6: frozen max + MFMA-computed denominator ----------------
__global__ __launch_bounds__(256) void attn_kernel(const u16* __restrict__ qkv,
                                                   const u16* __restrict__ vt,
                                                   u16* __restrict__ ctx) {
  int nwg = gridDim.x * gridDim.y;  // 1024
  int f = blockIdx.y * gridDim.x + blockIdx.x;
  int nf = (f & 7) * (nwg >> 3) + (f >> 3);
  int qblk = nf % gridDim.x, bh = nf / gridDim.x;
  int b = bh >> 4, h = bh & 15;
  int tid = threadIdx.x, w = tid >> 6, lane = tid & 63;
  int g = lane >> 4, l15 = lane & 15;
  int lr = lane >> 3, ch = lane & 7;
  int q0 = qblk * 64 + w * 16;
  const float SCALE = 0.125f * 1.44269504f;  // 1/sqrt(64) * log2(e)

  __shared__ __align__(16) u16 ks[2][64 * 64];
  __shared__ __align__(16) u16 vs[2][64 * 64];

  bf16x8 qf0, qf1;
  {
    const u16* qp = qkv + ((size_t)(q0 + l15) * BATCH + b) * 3072 + h * DHEAD;
    qf0 = *(const bf16x8*)(qp + g * 8);
    qf1 = *(const bf16x8*)(qp + 32 + g * 8);
  }
  bf16x8 onef;
  {
    union { u16 u[8]; bf16x8 v; } ou;
#pragma unroll
    for (int i = 0; i < 8; i++) ou.u[i] = 0x3F80;  // bf16 1.0
    onef = ou.v;
  }

  f32x4 accT[4];
#pragma unroll
  for (int n = 0; n < 4; n++) {
    f32x4 z = {0.f, 0.f, 0.f, 0.f};
    accT[n] = z;
  }
  f32x4 lacc = {0.f, 0.f, 0.f, 0.f};  // denominator (all rows equal)
  float negms = 0.f;                  // = -max_tile0 * SCALE, set at it==0

  auto stage = [&](int t0, int buf) {
#pragma unroll
    for (int rd = 0; rd < 2; rd++) {
      int rb = w * 16 + rd * 8;
      int row = rb + lr;
      const u16* ksrc =
          qkv + ((size_t)(t0 + row) * BATCH + b) * 3072 + 1024 + h * DHEAD + (ch ^ lr) * 8;
      gload_lds16(ksrc, &ks[buf][rb * 64]);
      const u16* vsrc = vt + ((size_t)bh * DHEAD + row) * S_LEN + t0 + (ch ^ lr) * 8;
      gload_lds16(vsrc, &vs[buf][rb * 64]);
    }
  };

  stage(0, 0);
  asm volatile("s_waitcnt vmcnt(0)" ::: "memory");
  __builtin_amdgcn_s_barrier();

  for (int it = 0; it < S_LEN / 64; ++it) {
    int cur = it & 1;
    if (it + 1 < S_LEN / 64) {
      stage((it + 1) * 64, cur ^ 1);
      asm volatile("s_waitcnt vmcnt(4)" ::: "memory");
    } else {
      asm volatile("s_waitcnt vmcnt(0)" ::: "memory");
    }
    __builtin_amdgcn_s_barrier();

    // ---- QK^T (swapped): scT[tt][r] = S_raw^T[16tt+4g+r][q0+l15] ----
    f32x4 scT[4];
#pragma unroll
    for (int tt = 0; tt < 4; tt++) {
      int row = tt * 16 + l15;
      bf16x8 kf0 = *(const bf16x8*)&ks[cur][row * 64 + ((g ^ (row & 7)) * 8)];
      bf16x8 kf1 = *(const bf16x8*)&ks[cur][row * 64 + (((4 + g) ^ (row & 7)) * 8)];
      f32x4 z = {0.f, 0.f, 0.f, 0.f};
      __builtin_amdgcn_s_setprio(1);
      z = mfma16(kf0, qf0, z);
      z = mfma16(kf1, qf1, z);
      __builtin_amdgcn_s_setprio(0);
      scT[tt] = z;
    }

    if (it == 0) {  // exact max of tile 0, then frozen
      float pm = fmaxf(fmaxf(scT[0][0], scT[0][1]), fmaxf(scT[0][2], scT[0][3]));
#pragma unroll
      for (int tt = 1; tt < 4; tt++)
        pm = fmaxf(pm, fmaxf(fmaxf(scT[tt][0], scT[tt][1]), fmaxf(scT[tt][2], scT[tt][3])));
      pm = fmaxf(pm, __shfl_xor(pm, 16));
      pm = fmaxf(pm, __shfl_xor(pm, 32));
      negms = -pm * SCALE;
    }

    // ---- p = exp2(s*SCALE + negms) ----
    float p[4][4];
#pragma unroll
    for (int tt = 0; tt < 4; tt++)
#pragma unroll
      for (int r = 0; r < 4; r++) p[tt][r] = __builtin_amdgcn_exp2f(fmaf(scT[tt][r], SCALE, negms));

    // ---- in-register P repack: reg=(t5,t4,t1),lane=(t3,t2) -> reg=(t5,t2,t1) ----
    uint32_t P32[4][2];
#pragma unroll
    for (int tt = 0; tt < 4; tt++)
#pragma unroll
      for (int m = 0; m < 2; m++) P32[tt][m] = cvt_pk_bf16(p[tt][2 * m], p[tt][2 * m + 1]);
#pragma unroll
    for (int t5 = 0; t5 < 2; t5++)
#pragma unroll
      for (int m = 0; m < 2; m++) {
        asm("v_permlane32_swap_b32 %0, %1" : "+v"(P32[2 * t5][m]), "+v"(P32[2 * t5 + 1][m]));
        asm("v_permlane16_swap_b32 %0, %1" : "+v"(P32[2 * t5][m]), "+v"(P32[2 * t5 + 1][m]));
      }
    bf16x8 pb[2];
#pragma unroll
    for (int s2 = 0; s2 < 2; s2++) {
      union { uint32_t u[4]; bf16x8 v; } uu;
      uu.u[0] = P32[2 * s2][0];
      uu.u[1] = P32[2 * s2][1];
      uu.u[2] = P32[2 * s2 + 1][0];
      uu.u[3] = P32[2 * s2 + 1][1];
      pb[s2] = uu.v;
    }

    // ---- PV (swapped) + denominator ----
    __builtin_amdgcn_s_setprio(1);
    lacc = mfma16(onef, pb[0], lacc);
    lacc = mfma16(onef, pb[1], lacc);
    __builtin_amdgcn_s_setprio(0);
#pragma unroll
    for (int n = 0; n < 4; n++) {
      int vrow = n * 16 + l15;
      bf16x8 vf0 = *(const bf16x8*)&vs[cur][vrow * 64 + ((g ^ (vrow & 7)) * 8)];
      bf16x8 vf1 = *(const bf16x8*)&vs[cur][vrow * 64 + (((4 + g) ^ (vrow & 7)) * 8)];
      __builtin_amdgcn_s_setprio(1);
      accT[n] = mfma16(vf0, pb[0], accT[n]);
      accT[n] = mfma16(vf1, pb[1], accT[n]);
      __builtin_amdgcn_s_setprio(0);
    }
    __builtin_amdgcn_s_barrier();
  }

  float inv = 1.f / lacc[0];
  int srow = q0 + l15;
#pragma unroll
  for (int n = 0; n < 4; n++) {
    u16x4 o;
    o.x = f2bf(accT[n][0] * inv);
    o.y = f2bf(accT[n][1] * inv);
    o.z = f2bf(accT[n][2] * inv);
    o.w = f2bf(accT[n][3] * inv);
    *(u16x4*)(ctx + ((size_t)srow * BATCH + b) * DMODEL + h * DHEAD + n * 16 + 4 * g) = o;
  }
}

extern "C" void kernel_launch(void* const* d_in, const int* in_sizes, int n_in, void* d_out,
                              int out_size, void* d_ws, size_t ws_size, hipStream_t stream) {
  (void)in_sizes; (void)n_in; (void)out_size; (void)ws_size;
  const float* x    = (const float*)d_in[0];
  const float* wq   = (const float*)d_in[1];
  const float* wk   = (const float*)d_in[2];
  const float* wv   = (const float*)d_in[3];
  const float* wo   = (const float*)d_in[4];
  const float* ln1g = (const float*)d_in[5];
  const float* ln1b = (const float*)d_in[6];
  const float* ln2g = (const float*)d_in[7];
  const float* ln2b = (const float*)d_in[8];
  const float* w1   = (const float*)d_in[9];
  const float* b1   = (const float*)d_in[10];
  const float* w2   = (const float*)d_in[11];
  const float* b2   = (const float*)d_in[12];

  char* ws = (char*)d_ws;
  size_t off = 0;
  auto alloc = [&](size_t bytes) {
    void* p = ws + off;
    off += (bytes + 255) & ~(size_t)255;
    return p;
  };
  u16* yb    = (u16*)alloc((size_t)MROWS * DMODEL * 2);
  u16* wqkvt = (u16*)alloc((size_t)3072 * 1024 * 2);
  u16* wot   = (u16*)alloc((size_t)1024 * 1024 * 2);
  u16* w1t   = (u16*)alloc((size_t)4096 * 1024 * 2);
  u16* w2t   = (u16*)alloc((size_t)1024 * 4096 * 2);
  u16* qkvb  = (u16*)alloc((size_t)MROWS * 3072 * 2);
  u16* vtb   = (u16*)alloc((size_t)BATCH * NHEAD * DHEAD * S_LEN * 2);
  u16* ctxb  = (u16*)alloc((size_t)MROWS * DMODEL * 2);
  float* x1  = (float*)alloc((size_t)MROWS * DMODEL * 4);
  u16* zb    = (u16*)alloc((size_t)MROWS * DMODEL * 2);
  u16* hb    = (u16*)alloc((size_t)MROWS * FFDIM * 2);

  // sublayer 0
  ln_kernel<<<MROWS, 256, 0, stream>>>(x, ln1g, ln1b, yb);
  transpose_all<<<12288, 256, 0, stream>>>(wq, wk, wv, wo, w1, w2, wqkvt, wot, w1t, w2t);

  gemm8<0><<<dim3(3072 / 256, 4096 / 256), 512, 0, stream>>>(yb, wqkvt, qkvb, nullptr, 4096, 3072,
                                                             1024);
  transpose_v<<<dim3(64, 2, 32), 256, 0, stream>>>(qkvb, vtb);
  attn_kernel<<<dim3(32, 32), 256, 0, stream>>>(qkvb, vtb, ctxb);
  gemm_bt<1, 64><<<dim3(16, 32), 256, 0, stream>>>(ctxb, wot, x1, nullptr, x, 4096, 1024, 1024);

  // sublayer 1
  ln_kernel<<<MROWS, 256, 0, stream>>>(x1, ln2g, ln2b, zb);
  gemm8<2><<<dim3(4096 / 256, 4096 / 256), 512, 0, stream>>>(zb, w1t, hb, b1, 4096, 4096, 1024);
  gemm_bt<3, 64><<<dim3(16, 32), 256, 0, stream>>>(hb, w2t, d_out, b2, x1, 4096, 1024, 4096);
}

// Round 10
// 243.584 us; speedup vs baseline: 1.1549x; 1.1549x over previous
//
#include <hip/hip_runtime.h>
#include <hip/hip_bf16.h>
#include <stdint.h>

// Transformer layer: S=2048, B=2, D=1024, H=16, DH=64, FF=4096. fp32 in/out.
// Strategy: fp32 LN/softmax/accum, bf16 MFMA (16x16x32) for all GEMMs.

#define S_LEN 2048
#define BATCH 2
#define DMODEL 1024
#define NHEAD 16
#define DHEAD 64
#define FFDIM 4096
#define MROWS (S_LEN * BATCH)  // 4096 rows, row index = s*B + b

typedef unsigned short u16;
typedef __attribute__((ext_vector_type(8))) __bf16 bf16x8;
typedef __attribute__((ext_vector_type(4))) float f32x4;
typedef __attribute__((ext_vector_type(4))) u16 u16x4;

__device__ inline u16 f2bf(float f) {
  union { float f; unsigned u; } v; v.f = f;
  unsigned r = v.u + 0x7fffu + ((v.u >> 16) & 1u);  // round-to-nearest-even
  return (u16)(r >> 16);
}

__device__ inline f32x4 mfma16(bf16x8 a, bf16x8 b, f32x4 c) {
  return __builtin_amdgcn_mfma_f32_16x16x32_bf16(a, b, c, 0, 0, 0);
}

// async global->LDS, 16B per lane. LDS dest must be wave-uniform base; HW adds lane*16.
__device__ inline void gload_lds16(const u16* g, u16* l) {
  __builtin_amdgcn_global_load_lds(
      (const __attribute__((address_space(1))) unsigned int*)g,
      (__attribute__((address_space(3))) unsigned int*)l, 16, 0, 0);
}

__device__ inline uint32_t cvt_pk_bf16(float lo, float hi) {
  uint32_t r;
  asm("v_cvt_pk_bf16_f32 %0, %1, %2" : "=v"(r) : "v"(lo), "v"(hi));
  return r;
}

// ---------------- LayerNorm: fp32 in -> bf16 out ----------------
__global__ __launch_bounds__(256) void ln_kernel(const float* __restrict__ x,
                                                 const float* __restrict__ gam,
                                                 const float* __restrict__ bet,
                                                 u16* __restrict__ out) {
  int row = blockIdx.x;
  int tid = threadIdx.x;
  const float4* xr = (const float4*)(x + (size_t)row * DMODEL);
  float4 v = xr[tid];
  float s = v.x + v.y + v.z + v.w;
  float ss = v.x * v.x + v.y * v.y + v.z * v.z + v.w * v.w;
#pragma unroll
  for (int m = 1; m < 64; m <<= 1) {
    s += __shfl_xor(s, m);
    ss += __shfl_xor(ss, m);
  }
  __shared__ float red[8];
  int w = tid >> 6, lane = tid & 63;
  if (lane == 0) { red[w] = s; red[4 + w] = ss; }
  __syncthreads();
  s = red[0] + red[1] + red[2] + red[3];
  ss = red[4] + red[5] + red[6] + red[7];
  float mu = s * (1.f / DMODEL);
  float var = ss * (1.f / DMODEL) - mu * mu;
  float rstd = rsqrtf(var + 1e-5f);
  float4 gv = ((const float4*)gam)[tid];
  float4 bv = ((const float4*)bet)[tid];
  u16x4 o;
  o.x = f2bf((v.x - mu) * rstd * gv.x + bv.x);
  o.y = f2bf((v.y - mu) * rstd * gv.y + bv.y);
  o.z = f2bf((v.z - mu) * rstd * gv.z + bv.z);
  o.w = f2bf((v.w - mu) * rstd * gv.w + bv.w);
  *(u16x4*)(out + (size_t)row * DMODEL + tid * 4) = o;
}

// ---------------- fused weight transpose-cast: all 6 weights in ONE launch ----------------
__global__ __launch_bounds__(256) void transpose_all(const float* __restrict__ wq,
                                                     const float* __restrict__ wk,
                                                     const float* __restrict__ wv,
                                                     const float* __restrict__ wo,
                                                     const float* __restrict__ w1,
                                                     const float* __restrict__ w2,
                                                     u16* __restrict__ wqkvt, u16* __restrict__ wot,
                                                     u16* __restrict__ w1t, u16* __restrict__ w2t) {
  int idx = blockIdx.x;
  const float* in;
  u16* out;
  int R, C;
  if (idx < 3072) {
    int which = idx >> 10;
    in = (which == 0) ? wq : (which == 1) ? wk : wv;
    out = wqkvt + (size_t)which * 1024 * 1024;
    R = 1024; C = 1024;
    idx &= 1023;
  } else if (idx < 4096) {
    in = wo; out = wot; R = 1024; C = 1024; idx -= 3072;
  } else if (idx < 8192) {
    in = w1; out = w1t; R = 1024; C = 4096; idx -= 4096;
  } else {
    in = w2; out = w2t; R = 4096; C = 1024; idx -= 8192;
  }
  int ntx = C >> 5;
  int tc = idx % ntx, tr = idx / ntx;
  int c0 = tc * 32, r0 = tr * 32;
  __shared__ u16 tile[32][33];
  int tx = threadIdx.x & 31, grp = threadIdx.x >> 5;
#pragma unroll
  for (int i = 0; i < 4; i++) {
    int r = grp * 4 + i;
    tile[r][tx] = f2bf(in[(size_t)(r0 + r) * C + c0 + tx]);
  }
  __syncthreads();
#pragma unroll
  for (int i = 0; i < 4; i++) {
    int rr = grp * 4 + i;
    out[(size_t)(c0 + rr) * R + r0 + tx] = tile[tx][rr];
  }
}

// ---------------- V slice of qkv -> Vt[bh][dh][s] ----------------
__global__ __launch_bounds__(256) void transpose_v(const u16* __restrict__ qkv,
                                                   u16* __restrict__ vt) {
  __shared__ u16 tile[32][33];
  int bh = blockIdx.z;
  int b = bh >> 4;
  int s0 = blockIdx.x * 32, d0 = blockIdx.y * 32;
  int h = bh & 15;
  int tx = threadIdx.x & 31, grp = threadIdx.x >> 5;
#pragma unroll
  for (int i = 0; i < 4; i++) {
    int sl = grp * 4 + i;
    tile[sl][tx] = qkv[(size_t)((s0 + sl) * BATCH + b) * 3072 + 2048 + h * DHEAD + d0 + tx];
  }
  __syncthreads();
#pragma unroll
  for (int i = 0; i < 4; i++) {
    int dl = grp * 4 + i;
    vt[((size_t)bh * DHEAD + d0 + dl) * S_LEN + s0 + tx] = tile[tx][dl];
  }
}

// ---------------- GEMM (R5/R8-proven): BK=64, XOR-swizzled LDS, counted-vmcnt 2-phase ----------------
// C[M][N] = A[M][K](bf16) @ Bt[N][K](bf16)^T.  BM=128, BN in {128,64}.
// Prefetch loads stay in flight across barriers; s_waitcnt vmcnt(NLOADS) waits only
// for the PREVIOUS tile's loads (never drains to 0 in the main loop).
// MODE 0: bf16 out.  MODE 1: fp32 out = acc + res.
// MODE 2: bf16 out = relu(acc + bias).  MODE 3: fp32 out = acc + bias + res.
template <int MODE, int BN>
__global__ __launch_bounds__(256) void gemm_bt(const u16* __restrict__ A,
                                               const u16* __restrict__ Bt, void* __restrict__ Cout,
                                               const float* __restrict__ bias,
                                               const float* __restrict__ res, int M, int N, int K) {
  __shared__ __align__(16) u16 As[2][128 * 64];
  __shared__ __align__(16) u16 Bs[2][BN * 64];
  constexpr int NLOADS = 4 + BN / 32;

  int nwg = gridDim.x * gridDim.y;
  int f = blockIdx.y * gridDim.x + blockIdx.x;
  int nf = ((nwg & 7) == 0) ? ((f & 7) * (nwg >> 3) + (f >> 3)) : f;
  int bx = nf % gridDim.x, by = nf / gridDim.x;

  int bm0 = by * 128, bn0 = bx * BN;
  int tid = threadIdx.x, w = tid >> 6, lane = tid & 63;
  int g = lane >> 4, l15 = lane & 15;
  int lr = lane >> 3, ch = lane & 7;
  int srcch = (ch ^ lr) * 8;  // pre-swizzled 16B-chunk column offset (rule 21c)
  int wm = (w >> 1) * 64, wn = (w & 1) * (BN / 2);
  const int NJ = BN / 32;

  f32x4 acc[4][NJ];
#pragma unroll
  for (int i = 0; i < 4; i++)
#pragma unroll
    for (int j = 0; j < NJ; j++) {
      f32x4 z = {0.f, 0.f, 0.f, 0.f};
      acc[i][j] = z;
    }

  auto stage = [&](int k0, int buf) {
#pragma unroll
    for (int rd = 0; rd < 4; rd++) {
      int rb = (rd * 4 + w) * 8;  // lane's row = rb + lr; row&7 == lr
      gload_lds16(A + (size_t)(bm0 + rb + lr) * K + k0 + srcch, &As[buf][rb * 64]);
    }
#pragma unroll
    for (int rd = 0; rd < BN / 32; rd++) {
      int rb = (rd * 4 + w) * 8;
      gload_lds16(Bt + (size_t)(bn0 + rb + lr) * K + k0 + srcch, &Bs[buf][rb * 64]);
    }
  };

  int nkt = K >> 6;
  stage(0, 0);
  asm volatile("s_waitcnt vmcnt(0)" ::: "memory");
  __builtin_amdgcn_s_barrier();

  for (int kt = 0; kt < nkt; ++kt) {
    int cur = kt & 1;
    if (kt + 1 < nkt) {
      stage((kt + 1) << 6, cur ^ 1);
      asm volatile("s_waitcnt vmcnt(%0)" ::"n"(NLOADS) : "memory");
    } else {
      asm volatile("s_waitcnt vmcnt(0)" ::: "memory");
    }
    __builtin_amdgcn_s_barrier();
#pragma unroll
    for (int kk = 0; kk < 2; kk++) {
      bf16x8 af[4], bfr[NJ];
#pragma unroll
      for (int i = 0; i < 4; i++) {
        int row = wm + i * 16 + l15;
        af[i] = *(const bf16x8*)&As[cur][row * 64 + (((kk * 4 + g) ^ (row & 7)) * 8)];
      }
#pragma unroll
      for (int j = 0; j < NJ; j++) {
        int row = wn + j * 16 + l15;
        bfr[j] = *(const bf16x8*)&Bs[cur][row * 64 + (((kk * 4 + g) ^ (row & 7)) * 8)];
      }
#pragma unroll
      for (int i = 0; i < 4; i++)
#pragma unroll
        for (int j = 0; j < NJ; j++) acc[i][j] = mfma16(af[i], bfr[j], acc[i][j]);
    }
    __builtin_amdgcn_s_barrier();
  }

  // epilogue: D layout col = lane&15, row = 4*(lane>>4) + r
#pragma unroll
  for (int i = 0; i < 4; i++)
#pragma unroll
    for (int j = 0; j < NJ; j++) {
      int col = bn0 + wn + j * 16 + l15;
      float bval = (MODE == 2 || MODE == 3) ? bias[col] : 0.f;
#pragma unroll
      for (int r = 0; r < 4; r++) {
        int row = bm0 + wm + i * 16 + g * 4 + r;
        size_t idx = (size_t)row * N + col;
        float vacc = acc[i][j][r] + bval;
        if (MODE == 0)
          ((u16*)Cout)[idx] = f2bf(vacc);
        else if (MODE == 1)
          ((float*)Cout)[idx] = vacc + res[idx];
        else if (MODE == 2)
          ((u16*)Cout)[idx] = f2bf(fmaxf(vacc, 0.f));
        else
          ((float*)Cout)[idx] = vacc + res[idx];
      }
    }
}

// ---------------- flash attention v7: deferred-PV pipeline (T15) ----------------
// grid (S/64, B*H) XCD-chunked, 256 thr = 4 waves; wave owns 16 q rows.
// Swapped mfma(K,Q): lane holds S^T[t][q=l15]. Frozen max after tile 0; denominator
// via ones-MFMA. NEW: PV is deferred one tile — iteration t runs QK(t), then PV(t-1)
// entirely from registers (pbp, vfp), then loads V(t) frags, then softmax(t)->pbp.
// The PV MFMA cluster + V ds_reads have no dep on softmax(t) => they execute under
// the softmax VALU (separate pipes). lgkmcnt(0) before the end barrier protects the
// deferred V reads from next iter's global_load_lds overwrite.
__global__ __launch_bounds__(256) void attn_kernel(const u16* __restrict__ qkv,
                                                   const u16* __restrict__ vt,
                                                   u16* __restrict__ ctx) {
  int nwg = gridDim.x * gridDim.y;  // 1024
  int f = blockIdx.y * gridDim.x + blockIdx.x;
  int nf = (f & 7) * (nwg >> 3) + (f >> 3);
  int qblk = nf % gridDim.x, bh = nf / gridDim.x;
  int b = bh >> 4, h = bh & 15;
  int tid = threadIdx.x, w = tid >> 6, lane = tid & 63;
  int g = lane >> 4, l15 = lane & 15;
  int lr = lane >> 3, ch = lane & 7;
  int q0 = qblk * 64 + w * 16;
  const float SCALE = 0.125f * 1.44269504f;  // 1/sqrt(64) * log2(e)

  __shared__ __align__(16) u16 ks[2][64 * 64];
  __shared__ __align__(16) u16 vs[2][64 * 64];

  bf16x8 qf0, qf1;
  {
    const u16* qp = qkv + ((size_t)(q0 + l15) * BATCH + b) * 3072 + h * DHEAD;
    qf0 = *(const bf16x8*)(qp + g * 8);
    qf1 = *(const bf16x8*)(qp + 32 + g * 8);
  }
  bf16x8 onef;
  {
    union { u16 u[8]; bf16x8 v; } ou;
#pragma unroll
    for (int i = 0; i < 8; i++) ou.u[i] = 0x3F80;  // bf16 1.0
    onef = ou.v;
  }

  f32x4 accT[4];
#pragma unroll
  for (int n = 0; n < 4; n++) {
    f32x4 z = {0.f, 0.f, 0.f, 0.f};
    accT[n] = z;
  }
  f32x4 lacc = {0.f, 0.f, 0.f, 0.f};  // denominator (all rows equal)
  float negms = 0.f;                  // = -max_tile0 * SCALE, set at it==0
  bf16x8 pbp[2];                      // P frags of previous tile
  bf16x8 vfp[4][2];                   // V frags of previous tile

  auto stage = [&](int t0, int buf) {
#pragma unroll
    for (int rd = 0; rd < 2; rd++) {
      int rb = w * 16 + rd * 8;
      int row = rb + lr;
      const u16* ksrc =
          qkv + ((size_t)(t0 + row) * BATCH + b) * 3072 + 1024 + h * DHEAD + (ch ^ lr) * 8;
      gload_lds16(ksrc, &ks[buf][rb * 64]);
      const u16* vsrc = vt + ((size_t)bh * DHEAD + row) * S_LEN + t0 + (ch ^ lr) * 8;
      gload_lds16(vsrc, &vs[buf][rb * 64]);
    }
  };

  stage(0, 0);
  asm volatile("s_waitcnt vmcnt(0)" ::: "memory");
  __builtin_amdgcn_s_barrier();

  for (int it = 0; it < S_LEN / 64; ++it) {
    int cur = it & 1;
    if (it + 1 < S_LEN / 64) {
      stage((it + 1) * 64, cur ^ 1);
      asm volatile("s_waitcnt vmcnt(4)" ::: "memory");
    } else {
      asm volatile("s_waitcnt vmcnt(0)" ::: "memory");
    }
    __builtin_amdgcn_s_barrier();

    // ---- QK^T(t) (swapped): scT[tt][r] = S_raw^T[16tt+4g+r][q0+l15] ----
    f32x4 scT[4];
#pragma unroll
    for (int tt = 0; tt < 4; tt++) {
      int row = tt * 16 + l15;
      bf16x8 kf0 = *(const bf16x8*)&ks[cur][row * 64 + ((g ^ (row & 7)) * 8)];
      bf16x8 kf1 = *(const bf16x8*)&ks[cur][row * 64 + (((4 + g) ^ (row & 7)) * 8)];
      f32x4 z = {0.f, 0.f, 0.f, 0.f};
      __builtin_amdgcn_s_setprio(1);
      z = mfma16(kf0, qf0, z);
      z = mfma16(kf1, qf1, z);
      __builtin_amdgcn_s_setprio(0);
      scT[tt] = z;
    }

    // ---- PV(t-1) + denominator: pure-register MFMA, independent of softmax(t) ----
    if (it > 0) {
      __builtin_amdgcn_s_setprio(1);
      lacc = mfma16(onef, pbp[0], lacc);
      lacc = mfma16(onef, pbp[1], lacc);
#pragma unroll
      for (int n = 0; n < 4; n++) {
        accT[n] = mfma16(vfp[n][0], pbp[0], accT[n]);
        accT[n] = mfma16(vfp[n][1], pbp[1], accT[n]);
      }
      __builtin_amdgcn_s_setprio(0);
    }

    // ---- load V(t) frags (consumed next iter); overlaps softmax VALU below ----
#pragma unroll
    for (int n = 0; n < 4; n++) {
      int vrow = n * 16 + l15;
      vfp[n][0] = *(const bf16x8*)&vs[cur][vrow * 64 + ((g ^ (vrow & 7)) * 8)];
      vfp[n][1] = *(const bf16x8*)&vs[cur][vrow * 64 + (((4 + g) ^ (vrow & 7)) * 8)];
    }

    // ---- softmax(t): frozen max, exp2, repack -> pbp (for next iter) ----
    if (it == 0) {
      float pm = fmaxf(fmaxf(scT[0][0], scT[0][1]), fmaxf(scT[0][2], scT[0][3]));
#pragma unroll
      for (int tt = 1; tt < 4; tt++)
        pm = fmaxf(pm, fmaxf(fmaxf(scT[tt][0], scT[tt][1]), fmaxf(scT[tt][2], scT[tt][3])));
      pm = fmaxf(pm, __shfl_xor(pm, 16));
      pm = fmaxf(pm, __shfl_xor(pm, 32));
      negms = -pm * SCALE;
    }
    float p[4][4];
#pragma unroll
    for (int tt = 0; tt < 4; tt++)
#pragma unroll
      for (int r = 0; r < 4; r++) p[tt][r] = __builtin_amdgcn_exp2f(fmaf(scT[tt][r], SCALE, negms));
    uint32_t P32[4][2];
#pragma unroll
    for (int tt = 0; tt < 4; tt++)
#pragma unroll
      for (int m = 0; m < 2; m++) P32[tt][m] = cvt_pk_bf16(p[tt][2 * m], p[tt][2 * m + 1]);
#pragma unroll
    for (int t5 = 0; t5 < 2; t5++)
#pragma unroll
      for (int m = 0; m < 2; m++) {
        asm("v_permlane32_swap_b32 %0, %1" : "+v"(P32[2 * t5][m]), "+v"(P32[2 * t5 + 1][m]));
        asm("v_permlane16_swap_b32 %0, %1" : "+v"(P32[2 * t5][m]), "+v"(P32[2 * t5 + 1][m]));
      }
#pragma unroll
    for (int s2 = 0; s2 < 2; s2++) {
      union { uint32_t u[4]; bf16x8 v; } uu;
      uu.u[0] = P32[2 * s2][0];
      uu.u[1] = P32[2 * s2][1];
      uu.u[2] = P32[2 * s2 + 1][0];
      uu.u[3] = P32[2 * s2 + 1][1];
      pbp[s2] = uu.v;
    }

    // deferred V reads must land before next iter's stage overwrites vs[cur]
    asm volatile("s_waitcnt lgkmcnt(0)" ::: "memory");
    __builtin_amdgcn_s_barrier();
  }

  // ---- epilogue: PV(last) ----
  lacc = mfma16(onef, pbp[0], lacc);
  lacc = mfma16(onef, pbp[1], lacc);
#pragma unroll
  for (int n = 0; n < 4; n++) {
    accT[n] = mfma16(vfp[n][0], pbp[0], accT[n]);
    accT[n] = mfma16(vfp[n][1], pbp[1], accT[n]);
  }

  float inv = 1.f / lacc[0];
  int srow = q0 + l15;
#pragma unroll
  for (int n = 0; n < 4; n++) {
    u16x4 o;
    o.x = f2bf(accT[n][0] * inv);
    o.y = f2bf(accT[n][1] * inv);
    o.z = f2bf(accT[n][2] * inv);
    o.w = f2bf(accT[n][3] * inv);
    *(u16x4*)(ctx + ((size_t)srow * BATCH + b) * DMODEL + h * DHEAD + n * 16 + 4 * g) = o;
  }
}

extern "C" void kernel_launch(void* const* d_in, const int* in_sizes, int n_in, void* d_out,
                              int out_size, void* d_ws, size_t ws_size, hipStream_t stream) {
  (void)in_sizes; (void)n_in; (void)out_size; (void)ws_size;
  const float* x    = (const float*)d_in[0];
  const float* wq   = (const float*)d_in[1];
  const float* wk   = (const float*)d_in[2];
  const float* wv   = (const float*)d_in[3];
  const float* wo   = (const float*)d_in[4];
  const float* ln1g = (const float*)d_in[5];
  const float* ln1b = (const float*)d_in[6];
  const float* ln2g = (const float*)d_in[7];
  const float* ln2b = (const float*)d_in[8];
  const float* w1   = (const float*)d_in[9];
  const float* b1   = (const float*)d_in[10];
  const float* w2   = (const float*)d_in[11];
  const float* b2   = (const float*)d_in[12];

  char* ws = (char*)d_ws;
  size_t off = 0;
  auto alloc = [&](size_t bytes) {
    void* p = ws + off;
    off += (bytes + 255) & ~(size_t)255;
    return p;
  };
  u16* yb    = (u16*)alloc((size_t)MROWS * DMODEL * 2);
  u16* wqkvt = (u16*)alloc((size_t)3072 * 1024 * 2);
  u16* wot   = (u16*)alloc((size_t)1024 * 1024 * 2);
  u16* w1t   = (u16*)alloc((size_t)4096 * 1024 * 2);
  u16* w2t   = (u16*)alloc((size_t)1024 * 4096 * 2);
  u16* qkvb  = (u16*)alloc((size_t)MROWS * 3072 * 2);
  u16* vtb   = (u16*)alloc((size_t)BATCH * NHEAD * DHEAD * S_LEN * 2);
  u16* ctxb  = (u16*)alloc((size_t)MROWS * DMODEL * 2);
  float* x1  = (float*)alloc((size_t)MROWS * DMODEL * 4);
  u16* zb    = (u16*)alloc((size_t)MROWS * DMODEL * 2);
  u16* hb    = (u16*)alloc((size_t)MROWS * FFDIM * 2);

  // sublayer 0
  ln_kernel<<<MROWS, 256, 0, stream>>>(x, ln1g, ln1b, yb);
  transpose_all<<<12288, 256, 0, stream>>>(wq, wk, wv, wo, w1, w2, wqkvt, wot, w1t, w2t);

  gemm_bt<0, 128><<<dim3(3072 / 128, 4096 / 128), 256, 0, stream>>>(yb, wqkvt, qkvb, nullptr,
                                                                    nullptr, 4096, 3072, 1024);
  transpose_v<<<dim3(64, 2, 32), 256, 0, stream>>>(qkvb, vtb);
  attn_kernel<<<dim3(32, 32), 256, 0, stream>>>(qkvb, vtb, ctxb);
  gemm_bt<1, 64><<<dim3(16, 32), 256, 0, stream>>>(ctxb, wot, x1, nullptr, x, 4096, 1024, 1024);

  // sublayer 1
  ln_kernel<<<MROWS, 256, 0, stream>>>(x1, ln2g, ln2b, zb);
  gemm_bt<2, 128><<<dim3(32, 32), 256, 0, stream>>>(zb, w1t, hb, b1, nullptr, 4096, 4096, 1024);
  gemm_bt<3, 64><<<dim3(16, 32), 256, 0, stream>>>(hb, w2t, d_out, b2, x1, 4096, 1024, 4096);
}